// Round 6
// baseline (117.280 us; speedup 1.0000x reference)
//
#include <hip/hip_runtime.h>
#include <hip/hip_bf16.h>
#include <stdint.h>

typedef __bf16 bf16;
typedef __bf16 bf16x8 __attribute__((ext_vector_type(8)));
typedef __bf16 bf16x4 __attribute__((ext_vector_type(4)));
typedef float  f32x4  __attribute__((ext_vector_type(4)));

#define MFMA16(A, B, C) __builtin_amdgcn_mfma_f32_16x16x32_bf16((A), (B), (C), 0, 0, 0)

static constexpr int Bsz = 4, Seq = 2048, Dm = 512, Hh = 8, Dh = 64;

__device__ __forceinline__ void g2l_16(void* lds, const void* gp) {
  __builtin_amdgcn_global_load_lds((__attribute__((address_space(1))) void*)gp,
                                   (__attribute__((address_space(3))) void*)lds, 16, 0, 0);
}

__device__ __forceinline__ float max3f(float a, float b, float c) {
  return fmaxf(fmaxf(a, b), c);   // clang fuses to v_max3_f32
}

// ---------------- LayerNorm fp32 -> bf16, one wave per row (D=512) ----------------
__global__ __launch_bounds__(256) void ln_cast_kernel(
    const float* __restrict__ x, const float* __restrict__ g,
    const float* __restrict__ be, bf16* __restrict__ xn) {
  const int row  = blockIdx.x * 4 + (threadIdx.x >> 6);
  const int lane = threadIdx.x & 63;
  const f32x4* xr = (const f32x4*)(x + (size_t)row * Dm);
  f32x4 v0 = xr[lane];
  f32x4 v1 = xr[lane + 64];
  float s = (v0.x + v0.y + v0.z + v0.w) + (v1.x + v1.y + v1.z + v1.w);
#pragma unroll
  for (int off = 32; off > 0; off >>= 1) s += __shfl_xor(s, off);
  const float mu = s * (1.0f / Dm);
  f32x4 d0 = v0 - mu, d1 = v1 - mu;
  float q = d0.x * d0.x + d0.y * d0.y + d0.z * d0.z + d0.w * d0.w
          + d1.x * d1.x + d1.y * d1.y + d1.z * d1.z + d1.w * d1.w;
#pragma unroll
  for (int off = 32; off > 0; off >>= 1) q += __shfl_xor(q, off);
  const float rs = rsqrtf(q * (1.0f / Dm) + 1e-5f);
  const f32x4* gr = (const f32x4*)g;
  const f32x4* br = (const f32x4*)be;
  f32x4 g0 = gr[lane], g1 = gr[lane + 64];
  f32x4 b0 = br[lane], b1 = br[lane + 64];
  f32x4 y0 = d0 * rs * g0 + b0;
  f32x4 y1 = d1 * rs * g1 + b1;
  bf16x4 o0 = { (bf16)y0.x, (bf16)y0.y, (bf16)y0.z, (bf16)y0.w };
  bf16x4 o1 = { (bf16)y1.x, (bf16)y1.y, (bf16)y1.z, (bf16)y1.w };
  bf16x4* orow = (bf16x4*)(xn + (size_t)row * Dm);
  orow[lane]      = o0;
  orow[lane + 64] = o1;
}

// ------- transpose + cast: src[R][C] f32 -> dst[C][R] bf16; rows < qrows get *qscale
__global__ __launch_bounds__(256) void tcast_kernel(
    const float* __restrict__ src, bf16* __restrict__ dst, int R, int C,
    int qrows, float qscale) {
  __shared__ float t[32][33];
  const int c0 = blockIdx.x * 32, r0 = blockIdx.y * 32;
  const int tx = threadIdx.x & 31, ty = threadIdx.x >> 5;
#pragma unroll
  for (int i = 0; i < 32; i += 8)
    t[ty + i][tx] = src[(size_t)(r0 + ty + i) * C + c0 + tx];
  __syncthreads();
#pragma unroll
  for (int i = 0; i < 32; i += 8) {
    const int rr = c0 + ty + i;
    const float sc = rr < qrows ? qscale : 1.0f;
    dst[(size_t)rr * R + r0 + tx] = (bf16)(t[tx][ty + i] * sc);
  }
}

// ---------------- QKV GEMM: [8192,512] x [512,1536] -> Q/K [B,H,S,64], V^T [B,H,64,S]
__global__ __launch_bounds__(256) void gemm_qkv_kernel(
    const bf16* __restrict__ A,   // [8192][512]
    const bf16* __restrict__ Bt,  // [1536][512]  (w_qkv transposed)
    bf16* __restrict__ Qb, bf16* __restrict__ Kb, bf16* __restrict__ VT) {
  constexpr int K = 512;
  __shared__ __align__(16) bf16 As[128 * 32];
  __shared__ __align__(16) bf16 Bs[128 * 32];
  const int m0 = blockIdx.x * 128, n0 = blockIdx.y * 128;
  const int tid = threadIdx.x, lane = tid & 63, wave = tid >> 6;
  const int lr = lane & 15, lg = lane >> 4;
  const int wm = (wave >> 1) * 64, wn = (wave & 1) * 64;
  const int srow = wave * 16 + (lane >> 2);
  const int scol = (lane & 3) * 8;
  const bf16* ga = A  + (size_t)(m0 + srow) * K + scol;
  const bf16* gb = Bt + (size_t)(n0 + srow) * K + scol;
  bf16* lA = As + wave * 512;
  bf16* lB = Bs + wave * 512;
  f32x4 acc[4][4] = {};
  for (int k0 = 0; k0 < K; k0 += 32) {
    g2l_16(lA,        ga + k0);
    g2l_16(lA + 2048, ga + (size_t)64 * K + k0);
    g2l_16(lB,        gb + k0);
    g2l_16(lB + 2048, gb + (size_t)64 * K + k0);
    asm volatile("s_waitcnt vmcnt(0)" ::: "memory");
    __syncthreads();
    bf16x8 af[4], bfr[4];
#pragma unroll
    for (int i = 0; i < 4; ++i)
      af[i] = *(const bf16x8*)&As[(wm + i * 16 + lr) * 32 + lg * 8];
#pragma unroll
    for (int j = 0; j < 4; ++j)
      bfr[j] = *(const bf16x8*)&Bs[(wn + j * 16 + lr) * 32 + lg * 8];
#pragma unroll
    for (int i = 0; i < 4; ++i)
#pragma unroll
      for (int j = 0; j < 4; ++j)
        acc[i][j] = MFMA16(af[i], bfr[j], acc[i][j]);
    __syncthreads();
  }
#pragma unroll
  for (int j = 0; j < 4; ++j) {
    const int n = n0 + wn + j * 16 + lr;
    const int which = n >> 9, h = (n >> 6) & 7, dh = n & 63;
    if (which < 2) {
      bf16* dst = which == 0 ? Qb : Kb;
#pragma unroll
      for (int i = 0; i < 4; ++i)
#pragma unroll
        for (int r = 0; r < 4; ++r) {
          const int m = m0 + wm + i * 16 + lg * 4 + r;
          const int b = m >> 11, s2 = m & 2047;
          dst[((size_t)((b * Hh + h) * Seq + s2) << 6) | dh] = (bf16)acc[i][j][r];
        }
    } else {
      // V: write transposed [bh][dh][s]
#pragma unroll
      for (int i = 0; i < 4; ++i)
#pragma unroll
        for (int r = 0; r < 4; ++r) {
          const int m = m0 + wm + i * 16 + lg * 4 + r;
          const int b = m >> 11, s2 = m & 2047;
          VT[((size_t)((b * Hh + h) * Dh + dh)) * Seq + s2] = (bf16)acc[i][j][r];
        }
    }
  }
}

// ---------------- Out GEMM: [8192,512] x [512,512] + bias -> fp32 out --------------
__global__ __launch_bounds__(256) void gemm_out_kernel(
    const bf16* __restrict__ A,   // [8192][512] attention output
    const bf16* __restrict__ Bt,  // [512][512]  (w_out transposed)
    const float* __restrict__ bias, float* __restrict__ out) {
  constexpr int K = 512;
  __shared__ __align__(16) bf16 As[128 * 32];
  __shared__ __align__(16) bf16 Bs[128 * 32];
  const int m0 = blockIdx.x * 128, n0 = blockIdx.y * 128;
  const int tid = threadIdx.x, lane = tid & 63, wave = tid >> 6;
  const int lr = lane & 15, lg = lane >> 4;
  const int wm = (wave >> 1) * 64, wn = (wave & 1) * 64;
  const int srow = wave * 16 + (lane >> 2);
  const int scol = (lane & 3) * 8;
  const bf16* ga = A  + (size_t)(m0 + srow) * K + scol;
  const bf16* gb = Bt + (size_t)(n0 + srow) * K + scol;
  bf16* lA = As + wave * 512;
  bf16* lB = Bs + wave * 512;
  f32x4 acc[4][4] = {};
  for (int k0 = 0; k0 < K; k0 += 32) {
    g2l_16(lA,        ga + k0);
    g2l_16(lA + 2048, ga + (size_t)64 * K + k0);
    g2l_16(lB,        gb + k0);
    g2l_16(lB + 2048, gb + (size_t)64 * K + k0);
    asm volatile("s_waitcnt vmcnt(0)" ::: "memory");
    __syncthreads();
    bf16x8 af[4], bfr[4];
#pragma unroll
    for (int i = 0; i < 4; ++i)
      af[i] = *(const bf16x8*)&As[(wm + i * 16 + lr) * 32 + lg * 8];
#pragma unroll
    for (int j = 0; j < 4; ++j)
      bfr[j] = *(const bf16x8*)&Bs[(wn + j * 16 + lr) * 32 + lg * 8];
#pragma unroll
    for (int i = 0; i < 4; ++i)
#pragma unroll
      for (int j = 0; j < 4; ++j)
        acc[i][j] = MFMA16(af[i], bfr[j], acc[i][j]);
    __syncthreads();
  }
#pragma unroll
  for (int j = 0; j < 4; ++j) {
    const int n = n0 + wn + j * 16 + lr;
    const float bv = bias[n];
#pragma unroll
    for (int i = 0; i < 4; ++i)
#pragma unroll
      for (int r = 0; r < 4; ++r) {
        const int m = m0 + wm + i * 16 + lg * 4 + r;
        out[(size_t)m * 512 + n] = acc[i][j][r] + bv;
      }
  }
}

// ------- Flash attention v6: 4 waves x 32 q — K/V LDS reads amortized over 2x FLOP -
// QBLK=128 (4 waves x 32 q), KVBLK=64. Compile-time dbuf, swizzled K/V staging,
// in-register softmax (exp2 domain, defer-max THR=3), ones-MFMA row-sum,
// s_setprio(1) around MFMA clusters (T5, attn-positive per m191).
__global__ __launch_bounds__(256) void attn6_kernel(
    const bf16* __restrict__ Qb, const bf16* __restrict__ Kb,
    const bf16* __restrict__ VT, bf16* __restrict__ A2) {
  // bijective XCD-chunked swizzle: 512 blocks -> 64/XCD -> 4 complete heads/XCD
  const int o   = blockIdx.x + gridDim.x * blockIdx.y;  // 0..511
  const int nid = ((o & 7) << 6) + (o >> 3);
  const int qc = nid & 15, bh = nid >> 4;
  const int b = bh >> 3, h = bh & 7;
  const int tid = threadIdx.x, lane = tid & 63, wave = tid >> 6;
  const int lr = lane & 15, lg = lane >> 4;
  const int q0 = qc * 128 + wave * 32;
  const bf16* Qh = Qb + (size_t)bh * Seq * Dh;
  const bf16* Kh = Kb + (size_t)bh * Seq * Dh;
  const bf16* Vh = VT + (size_t)bh * Dh * Seq;

  // KV[buf] : elements [0,4096) = K tile (swizzled), [4096,8192) = V tile (swizzled)
  __shared__ __align__(16) bf16 KV[2][8192];
  __shared__ __align__(16) bf16 Pl[4][2][16][72];

  // hoisted per-lane LDS bases (elements)
  const int xs   = lr & 7;
  const int col0 = (lg ^ xs) * 8;
  const bf16* kv = &KV[0][0];
  const int kb0 = lr * 64 + col0;          // frag0 base
  const int kb1 = lr * 64 + (col0 ^ 32);   // frag1 base
  bf16* pw0 = &Pl[wave][0][lr][lg * 4];
  bf16* pw1 = &Pl[wave][1][lr][lg * 4];
  const bf16* pr0 = &Pl[wave][0][lr][lg * 8];
  const bf16* pr1 = &Pl[wave][1][lr][lg * 8];

  // staging: 256 threads x 16B = 4KB/round; K rounds at [0,2048),[2048,4096) elems
  const int krow = tid >> 3;                       // 0..31
  const int kc   = (((tid & 7) ^ (krow & 7)) * 8);
  const bf16* gK = Kh + (size_t)krow * 64 + kc;
  const bf16* gV = Vh + (size_t)krow * Seq + kc;
  bf16* ldsD = &KV[0][0] + tid * 8;

  bf16x8 qf[2][2];
#pragma unroll
  for (int qb = 0; qb < 2; ++qb) {
    qf[qb][0] = *(const bf16x8*)&Qh[(size_t)(q0 + qb * 16 + lr) * 64 + lg * 8];
    qf[qb][1] = *(const bf16x8*)&Qh[(size_t)(q0 + qb * 16 + lr) * 64 + 32 + lg * 8];
  }

  f32x4 oa[2][4] = {};
  f32x4 ol[2] = {};
  float m[2] = { -1e30f, -1e30f };
  bf16x8 ones;
#pragma unroll
  for (int i = 0; i < 8; ++i) ones[i] = (bf16)1.0f;

  auto STAGE = [&](int dstOff, int t0) {   // dstOff: 0 or 8192 (buf), t0 in keys
    g2l_16(ldsD + dstOff,        gK + (size_t)t0 * 64);
    g2l_16(ldsD + dstOff + 2048, gK + (size_t)t0 * 64 + 2048);  // K rows 32..63
    g2l_16(ldsD + dstOff + 4096, gV + t0);
    g2l_16(ldsD + dstOff + 6144, gV + (size_t)32 * Seq + t0);   // V rows 32..63
  };

  auto TILE = [&](int buf) {   // buf is a literal at every call site
    const int kB = buf * 8192;
    // S^T = K Q'^T : lane holds Z[k = c*16+lg*4+j][q = q0+qb*16+lr]
    f32x4 st[2][4] = {};
    __builtin_amdgcn_s_setprio(1);
#pragma unroll
    for (int c = 0; c < 4; ++c) {
      bf16x8 kf0 = *(const bf16x8*)&kv[kb0 + kB + c * 1024];
      bf16x8 kf1 = *(const bf16x8*)&kv[kb1 + kB + c * 1024];
      st[0][c] = MFMA16(kf0, qf[0][0], st[0][c]);
      st[0][c] = MFMA16(kf1, qf[0][1], st[0][c]);
      st[1][c] = MFMA16(kf0, qf[1][0], st[1][c]);
      st[1][c] = MFMA16(kf1, qf[1][1], st[1][c]);
    }
    __builtin_amdgcn_s_setprio(0);
    // online softmax per q-block: max3 tree + 2 shuffles; defer-max THR=3
#pragma unroll
    for (int qb = 0; qb < 2; ++qb) {
      float m0 = max3f(st[qb][0][0], st[qb][0][1], st[qb][0][2]);
      float m1 = max3f(st[qb][0][3], st[qb][1][0], st[qb][1][1]);
      float m2 = max3f(st[qb][1][2], st[qb][1][3], st[qb][2][0]);
      float m3 = max3f(st[qb][2][1], st[qb][2][2], st[qb][2][3]);
      float m4 = max3f(st[qb][3][0], st[qb][3][1], st[qb][3][2]);
      float mx = max3f(max3f(m0, m1, m2), m3, fmaxf(m4, st[qb][3][3]));
      mx = fmaxf(mx, __shfl_xor(mx, 16));
      mx = fmaxf(mx, __shfl_xor(mx, 32));
      if (__any(mx > m[qb] + 3.0f)) {
        const float mn = fmaxf(m[qb], mx);
        const float al = exp2f(m[qb] - mn);
        m[qb] = mn;
#pragma unroll
        for (int j = 0; j < 4; ++j) {
          const float aj = __shfl(al, lg * 4 + j);
          ol[qb][j] *= aj;
#pragma unroll
          for (int n = 0; n < 4; ++n) oa[qb][n][j] *= aj;
        }
      }
      bf16* pw = qb ? pw1 : pw0;
#pragma unroll
      for (int c = 0; c < 4; ++c) {
        bf16x4 pk;
#pragma unroll
        for (int j = 0; j < 4; ++j) pk[j] = (bf16)exp2f(st[qb][c][j] - m[qb]);
        *(bf16x4*)&pw[c * 16] = pk;          // imm offset c*32 bytes
      }
    }
    // PV + ones-MFMA row-sum; V fragments shared across both q-blocks
    bf16x8 pf[2][2];
    pf[0][0] = *(const bf16x8*)&pr0[0];
    pf[0][1] = *(const bf16x8*)&pr0[32];
    pf[1][0] = *(const bf16x8*)&pr1[0];
    pf[1][1] = *(const bf16x8*)&pr1[32];
    __builtin_amdgcn_s_setprio(1);
    ol[0] = MFMA16(pf[0][0], ones, ol[0]);
    ol[0] = MFMA16(pf[0][1], ones, ol[0]);
    ol[1] = MFMA16(pf[1][0], ones, ol[1]);
    ol[1] = MFMA16(pf[1][1], ones, ol[1]);
#pragma unroll
    for (int n = 0; n < 4; ++n) {
      bf16x8 vf0 = *(const bf16x8*)&kv[kb0 + kB + 4096 + n * 1024];
      bf16x8 vf1 = *(const bf16x8*)&kv[kb1 + kB + 4096 + n * 1024];
      oa[0][n] = MFMA16(pf[0][0], vf0, oa[0][n]);
      oa[0][n] = MFMA16(pf[0][1], vf1, oa[0][n]);
      oa[1][n] = MFMA16(pf[1][0], vf0, oa[1][n]);
      oa[1][n] = MFMA16(pf[1][1], vf1, oa[1][n]);
    }
    __builtin_amdgcn_s_setprio(0);
  };

  // prologue: stage tile 0 into buf0
  STAGE(0, 0);
  asm volatile("s_waitcnt vmcnt(0)" ::: "memory");
  __syncthreads();

  for (int it = 0; it < 16; ++it) {
    const int t0 = it * 128;
    STAGE(8192, t0 + 64);                    // stage odd tile into buf1
    TILE(0);
    asm volatile("s_waitcnt vmcnt(0)" ::: "memory");
    __syncthreads();
    if (it < 15) STAGE(0, t0 + 128);         // stage even tile into buf0
    TILE(1);
    asm volatile("s_waitcnt vmcnt(0)" ::: "memory");
    __syncthreads();
  }

  // epilogue: normalize (l held in-lane), write [B*S, 512] bf16
#pragma unroll
  for (int qb = 0; qb < 2; ++qb) {
#pragma unroll
    for (int j = 0; j < 4; ++j) {
      const float lj = 1.0f / ol[qb][j];
      const int s2 = q0 + qb * 16 + lg * 4 + j;
#pragma unroll
      for (int n = 0; n < 4; ++n)
        A2[(size_t)(b * Seq + s2) * 512 + h * 64 + n * 16 + lr] = (bf16)(oa[qb][n][j] * lj);
    }
  }
}

extern "C" void kernel_launch(void* const* d_in, const int* in_sizes, int n_in,
                              void* d_out, int out_size, void* d_ws, size_t ws_size,
                              hipStream_t stream) {
  const float* x    = (const float*)d_in[0];
  const float* gam  = (const float*)d_in[1];
  const float* bet  = (const float*)d_in[2];
  const float* wqkv = (const float*)d_in[3];  // [512][1536]
  const float* wout = (const float*)d_in[4];  // [512][512]
  const float* bout = (const float*)d_in[5];  // [512]
  float* out = (float*)d_out;

  bf16* xn    = (bf16*)d_ws;                        // [8192][512]   8 MB
  bf16* wqkvT = xn    + (size_t)8192 * 512;         // [1536][512]   1.5 MB
  bf16* woutT = wqkvT + (size_t)1536 * 512;         // [512][512]    0.5 MB
  bf16* Qb    = woutT + (size_t)512 * 512;          // [4,8,2048,64] 8 MB
  bf16* Kb    = Qb    + (size_t)4 * 8 * 2048 * 64;
  bf16* VT    = Kb    + (size_t)4 * 8 * 2048 * 64;  // [4,8,64,2048] 8 MB
  bf16* A2    = xn;  // reuse: xn dead after QKV GEMM

  // 64^-0.5 * log2(e) folded into Q columns of w_qkv
  const float K1 = 0.18033688011112042f;

  ln_cast_kernel<<<2048, 256, 0, stream>>>(x, gam, bet, xn);
  tcast_kernel<<<dim3(48, 16), 256, 0, stream>>>(wqkv, wqkvT, 512, 1536, 512, K1);
  tcast_kernel<<<dim3(16, 16), 256, 0, stream>>>(wout, woutT, 512, 512, 0, 1.0f);
  gemm_qkv_kernel<<<dim3(64, 12), 256, 0, stream>>>(xn, wqkvT, Qb, Kb, VT);
  attn6_kernel<<<dim3(16, 32), 256, 0, stream>>>(Qb, Kb, VT, A2);
  gemm_out_kernel<<<dim3(64, 4), 256, 0, stream>>>(A2, woutT, bout, out);
}

// Round 7
// 114.507 us; speedup vs baseline: 1.0242x; 1.0242x over previous
//
#include <hip/hip_runtime.h>
#include <hip/hip_bf16.h>
#include <stdint.h>

typedef __bf16 bf16;
typedef __bf16 bf16x8 __attribute__((ext_vector_type(8)));
typedef __bf16 bf16x4 __attribute__((ext_vector_type(4)));
typedef float  f32x4  __attribute__((ext_vector_type(4)));
typedef float  f32x16 __attribute__((ext_vector_type(16)));

#define MFMA16(A, B, C) __builtin_amdgcn_mfma_f32_16x16x32_bf16((A), (B), (C), 0, 0, 0)
#define MFMA32(A, B, C) __builtin_amdgcn_mfma_f32_32x32x16_bf16((A), (B), (C), 0, 0, 0)

static constexpr int Bsz = 4, Seq = 2048, Dm = 512, Hh = 8, Dh = 64;

__device__ __forceinline__ void g2l_16(void* lds, const void* gp) {
  __builtin_amdgcn_global_load_lds((__attribute__((address_space(1))) void*)gp,
                                   (__attribute__((address_space(3))) void*)lds, 16, 0, 0);
}

__device__ __forceinline__ float max3f(float a, float b, float c) {
  return fmaxf(fmaxf(a, b), c);   // clang fuses to v_max3_f32
}

// ---------------- LayerNorm fp32 -> bf16, one wave per row (D=512) ----------------
__global__ __launch_bounds__(256) void ln_cast_kernel(
    const float* __restrict__ x, const float* __restrict__ g,
    const float* __restrict__ be, bf16* __restrict__ xn) {
  const int row  = blockIdx.x * 4 + (threadIdx.x >> 6);
  const int lane = threadIdx.x & 63;
  const f32x4* xr = (const f32x4*)(x + (size_t)row * Dm);
  f32x4 v0 = xr[lane];
  f32x4 v1 = xr[lane + 64];
  float s = (v0.x + v0.y + v0.z + v0.w) + (v1.x + v1.y + v1.z + v1.w);
#pragma unroll
  for (int off = 32; off > 0; off >>= 1) s += __shfl_xor(s, off);
  const float mu = s * (1.0f / Dm);
  f32x4 d0 = v0 - mu, d1 = v1 - mu;
  float q = d0.x * d0.x + d0.y * d0.y + d0.z * d0.z + d0.w * d0.w
          + d1.x * d1.x + d1.y * d1.y + d1.z * d1.z + d1.w * d1.w;
#pragma unroll
  for (int off = 32; off > 0; off >>= 1) q += __shfl_xor(q, off);
  const float rs = rsqrtf(q * (1.0f / Dm) + 1e-5f);
  const f32x4* gr = (const f32x4*)g;
  const f32x4* br = (const f32x4*)be;
  f32x4 g0 = gr[lane], g1 = gr[lane + 64];
  f32x4 b0 = br[lane], b1 = br[lane + 64];
  f32x4 y0 = d0 * rs * g0 + b0;
  f32x4 y1 = d1 * rs * g1 + b1;
  bf16x4 o0 = { (bf16)y0.x, (bf16)y0.y, (bf16)y0.z, (bf16)y0.w };
  bf16x4 o1 = { (bf16)y1.x, (bf16)y1.y, (bf16)y1.z, (bf16)y1.w };
  bf16x4* orow = (bf16x4*)(xn + (size_t)row * Dm);
  orow[lane]      = o0;
  orow[lane + 64] = o1;
}

// ------- transpose + cast: src[R][C] f32 -> dst[C][R] bf16; rows < qrows get *qscale
__global__ __launch_bounds__(256) void tcast_kernel(
    const float* __restrict__ src, bf16* __restrict__ dst, int R, int C,
    int qrows, float qscale) {
  __shared__ float t[32][33];
  const int c0 = blockIdx.x * 32, r0 = blockIdx.y * 32;
  const int tx = threadIdx.x & 31, ty = threadIdx.x >> 5;
#pragma unroll
  for (int i = 0; i < 32; i += 8)
    t[ty + i][tx] = src[(size_t)(r0 + ty + i) * C + c0 + tx];
  __syncthreads();
#pragma unroll
  for (int i = 0; i < 32; i += 8) {
    const int rr = c0 + ty + i;
    const float sc = rr < qrows ? qscale : 1.0f;
    dst[(size_t)rr * R + r0 + tx] = (bf16)(t[tx][ty + i] * sc);
  }
}

// ---------------- QKV GEMM: [8192,512] x [512,1536] -> Q/K [B,H,S,64], V^T [B,H,64,S]
__global__ __launch_bounds__(256) void gemm_qkv_kernel(
    const bf16* __restrict__ A,   // [8192][512]
    const bf16* __restrict__ Bt,  // [1536][512]  (w_qkv transposed)
    bf16* __restrict__ Qb, bf16* __restrict__ Kb, bf16* __restrict__ VT) {
  constexpr int K = 512;
  __shared__ __align__(16) bf16 As[128 * 32];
  __shared__ __align__(16) bf16 Bs[128 * 32];
  const int m0 = blockIdx.x * 128, n0 = blockIdx.y * 128;
  const int tid = threadIdx.x, lane = tid & 63, wave = tid >> 6;
  const int lr = lane & 15, lg = lane >> 4;
  const int wm = (wave >> 1) * 64, wn = (wave & 1) * 64;
  const int srow = wave * 16 + (lane >> 2);
  const int scol = (lane & 3) * 8;
  const bf16* ga = A  + (size_t)(m0 + srow) * K + scol;
  const bf16* gb = Bt + (size_t)(n0 + srow) * K + scol;
  bf16* lA = As + wave * 512;
  bf16* lB = Bs + wave * 512;
  f32x4 acc[4][4] = {};
  for (int k0 = 0; k0 < K; k0 += 32) {
    g2l_16(lA,        ga + k0);
    g2l_16(lA + 2048, ga + (size_t)64 * K + k0);
    g2l_16(lB,        gb + k0);
    g2l_16(lB + 2048, gb + (size_t)64 * K + k0);
    asm volatile("s_waitcnt vmcnt(0)" ::: "memory");
    __syncthreads();
    bf16x8 af[4], bfr[4];
#pragma unroll
    for (int i = 0; i < 4; ++i)
      af[i] = *(const bf16x8*)&As[(wm + i * 16 + lr) * 32 + lg * 8];
#pragma unroll
    for (int j = 0; j < 4; ++j)
      bfr[j] = *(const bf16x8*)&Bs[(wn + j * 16 + lr) * 32 + lg * 8];
#pragma unroll
    for (int i = 0; i < 4; ++i)
#pragma unroll
      for (int j = 0; j < 4; ++j)
        acc[i][j] = MFMA16(af[i], bfr[j], acc[i][j]);
    __syncthreads();
  }
#pragma unroll
  for (int j = 0; j < 4; ++j) {
    const int n = n0 + wn + j * 16 + lr;
    const int which = n >> 9, h = (n >> 6) & 7, dh = n & 63;
    if (which < 2) {
      bf16* dst = which == 0 ? Qb : Kb;
#pragma unroll
      for (int i = 0; i < 4; ++i)
#pragma unroll
        for (int r = 0; r < 4; ++r) {
          const int m = m0 + wm + i * 16 + lg * 4 + r;
          const int b = m >> 11, s2 = m & 2047;
          dst[((size_t)((b * Hh + h) * Seq + s2) << 6) | dh] = (bf16)acc[i][j][r];
        }
    } else {
      // V: write transposed [bh][dh][s]
#pragma unroll
      for (int i = 0; i < 4; ++i)
#pragma unroll
        for (int r = 0; r < 4; ++r) {
          const int m = m0 + wm + i * 16 + lg * 4 + r;
          const int b = m >> 11, s2 = m & 2047;
          VT[((size_t)((b * Hh + h) * Dh + dh)) * Seq + s2] = (bf16)acc[i][j][r];
        }
    }
  }
}

// ---------------- Out GEMM: [8192,512] x [512,512] + bias -> fp32 out --------------
__global__ __launch_bounds__(256) void gemm_out_kernel(
    const bf16* __restrict__ A,   // [8192][512] attention output
    const bf16* __restrict__ Bt,  // [512][512]  (w_out transposed)
    const float* __restrict__ bias, float* __restrict__ out) {
  constexpr int K = 512;
  __shared__ __align__(16) bf16 As[128 * 32];
  __shared__ __align__(16) bf16 Bs[128 * 32];
  const int m0 = blockIdx.x * 128, n0 = blockIdx.y * 128;
  const int tid = threadIdx.x, lane = tid & 63, wave = tid >> 6;
  const int lr = lane & 15, lg = lane >> 4;
  const int wm = (wave >> 1) * 64, wn = (wave & 1) * 64;
  const int srow = wave * 16 + (lane >> 2);
  const int scol = (lane & 3) * 8;
  const bf16* ga = A  + (size_t)(m0 + srow) * K + scol;
  const bf16* gb = Bt + (size_t)(n0 + srow) * K + scol;
  bf16* lA = As + wave * 512;
  bf16* lB = Bs + wave * 512;
  f32x4 acc[4][4] = {};
  for (int k0 = 0; k0 < K; k0 += 32) {
    g2l_16(lA,        ga + k0);
    g2l_16(lA + 2048, ga + (size_t)64 * K + k0);
    g2l_16(lB,        gb + k0);
    g2l_16(lB + 2048, gb + (size_t)64 * K + k0);
    asm volatile("s_waitcnt vmcnt(0)" ::: "memory");
    __syncthreads();
    bf16x8 af[4], bfr[4];
#pragma unroll
    for (int i = 0; i < 4; ++i)
      af[i] = *(const bf16x8*)&As[(wm + i * 16 + lr) * 32 + lg * 8];
#pragma unroll
    for (int j = 0; j < 4; ++j)
      bfr[j] = *(const bf16x8*)&Bs[(wn + j * 16 + lr) * 32 + lg * 8];
#pragma unroll
    for (int i = 0; i < 4; ++i)
#pragma unroll
      for (int j = 0; j < 4; ++j)
        acc[i][j] = MFMA16(af[i], bfr[j], acc[i][j]);
    __syncthreads();
  }
#pragma unroll
  for (int j = 0; j < 4; ++j) {
    const int n = n0 + wn + j * 16 + lr;
    const float bv = bias[n];
#pragma unroll
    for (int i = 0; i < 4; ++i)
#pragma unroll
      for (int r = 0; r < 4; ++r) {
        const int m = m0 + wm + i * 16 + lg * 4 + r;
        out[(size_t)m * 512 + n] = acc[i][j][r] + bv;
      }
  }
}

// ------- Flash attention v7: 32x32x16 MFMA, 4 waves x 32 q, one softmax/tile -------
// QBLK=128, KVBLK=64. S^T C/D: col=q=lane&31, row=k=(reg&3)+8(reg>>2)+4(lane>>5).
// Lane pair (l, l^32) covers all 64 k of one q -> single shfl_xor(32) reduce.
// P staged per-wave in swizzled LDS [32][64]; ones-MFMA row-sum shares oa's layout.
__global__ __launch_bounds__(256) void attn7_kernel(
    const bf16* __restrict__ Qb, const bf16* __restrict__ Kb,
    const bf16* __restrict__ VT, bf16* __restrict__ A2) {
  // bijective XCD-chunked swizzle: 512 blocks -> 64/XCD -> 4 complete heads/XCD
  const int o   = blockIdx.x + gridDim.x * blockIdx.y;  // 0..511
  const int nid = ((o & 7) << 6) + (o >> 3);
  const int qc = nid & 15, bh = nid >> 4;
  const int b = bh >> 3, h = bh & 7;
  const int tid = threadIdx.x, lane = tid & 63, wave = tid >> 6;
  const int q_l = lane & 31, h5 = lane >> 5;
  const int kx  = q_l & 7;                 // XOR swizzle class (row&7 for all our rows)
  const int q0w = qc * 128 + wave * 32;
  const bf16* Qh = Qb + (size_t)bh * Seq * Dh;
  const bf16* Kh = Kb + (size_t)bh * Seq * Dh;
  const bf16* Vh = VT + (size_t)bh * Dh * Seq;

  // KV[buf]: [0,4096) = K tile 64x64 (swizzled), [4096,8192) = V^T tile 64x64
  __shared__ __align__(16) bf16 KV[2][8192];
  __shared__ __align__(16) bf16 Pl[4][32 * 64];   // per-wave P, swizzled

  const bf16* kv = &KV[0][0];
  bf16* Pw = &Pl[wave][q_l * 64];

  // staging: 256 threads x 16B x 4 rounds per buffer (attn6-verified pattern)
  const int krow = tid >> 3;                        // 0..31
  const int kc   = (((tid & 7) ^ (krow & 7)) * 8);  // pre-swizzled source col
  const bf16* gK = Kh + (size_t)krow * 64 + kc;
  const bf16* gV = Vh + (size_t)krow * Seq + kc;
  bf16* ldsD = &KV[0][0] + tid * 8;

  auto STAGE = [&](int dstOff, int t0) {
    g2l_16(ldsD + dstOff,        gK + (size_t)t0 * 64);
    g2l_16(ldsD + dstOff + 2048, gK + (size_t)t0 * 64 + 2048);  // K rows 32..63
    g2l_16(ldsD + dstOff + 4096, gV + t0);
    g2l_16(ldsD + dstOff + 6144, gV + (size_t)32 * Seq + t0);   // V rows 32..63
  };

  // Q B-fragments: qfr[s][i] = Q[q0w+q_l][16s + 8*h5 + i]  (held in 16 VGPRs)
  bf16x8 qfr[4];
#pragma unroll
  for (int s = 0; s < 4; ++s)
    qfr[s] = *(const bf16x8*)&Qh[(size_t)(q0w + q_l) * 64 + 16 * s + 8 * h5];

  f32x16 oa0 = {}, oa1 = {}, ol = {};
  float m = -1e30f;
  bf16x8 ones;
#pragma unroll
  for (int i = 0; i < 8; ++i) ones[i] = (bf16)1.0f;

  auto TILE = [&](int buf) {   // buf literal at each call site
    const int kB = buf * 8192;
    // ---- S^T = K Q'^T (exp2-scaled Q): st0 = k rows 0..31, st1 = 32..63
    f32x16 st0 = {}, st1 = {};
    __builtin_amdgcn_s_setprio(1);
#pragma unroll
    for (int s = 0; s < 4; ++s) {
      const int eoff = ((2 * s + h5) ^ kx) << 3;
      bf16x8 kf0 = *(const bf16x8*)&kv[kB + q_l * 64 + eoff];
      bf16x8 kf1 = *(const bf16x8*)&kv[kB + (32 + q_l) * 64 + eoff];
      st0 = MFMA32(kf0, qfr[s], st0);
      st1 = MFMA32(kf1, qfr[s], st1);
    }
    __builtin_amdgcn_s_setprio(0);
    // ---- softmax: in-lane max over 32 + one cross-lane (lane^32 completes 64 k)
    float mx = max3f(st0[0], st0[1], st1[0]);
#pragma unroll
    for (int r = 1; r < 8; ++r) mx = max3f(st0[2 * r], st0[2 * r + 1], mx);
#pragma unroll
    for (int r = 0; r < 5; ++r) mx = max3f(st1[2 * r + 1], st1[2 * r + 2], mx);
    mx = max3f(st1[11], st1[12], mx);
    mx = max3f(st1[13], st1[14], mx);
    mx = fmaxf(st1[15], mx);
    mx = fmaxf(mx, __shfl_xor(mx, 32));
    if (__any(mx > m + 3.0f)) {            // defer-max THR=3 (exp2 domain)
      const float mn = fmaxf(m, mx);
      const float al = exp2f(m - mn);
      m = mn;
#pragma unroll
      for (int r = 0; r < 16; ++r) {
        const int qr = (r & 3) + 8 * (r >> 2) + 4 * h5;
        const float aj = __shfl(al, qr);   // al lives at lanes {qr, qr+32}, equal
        ol[r] *= aj; oa0[r] *= aj; oa1[r] *= aj;
      }
    }
    // ---- P = exp2(st - m) -> bf16 -> swizzled LDS  (quad (t,kb): k = 32kb+8t+4h5+j)
#pragma unroll
    for (int t = 0; t < 4; ++t) {
      bf16x4 p0, p1;
#pragma unroll
      for (int j = 0; j < 4; ++j) {
        p0[j] = (bf16)exp2f(st0[4 * t + j] - m);
        p1[j] = (bf16)exp2f(st1[4 * t + j] - m);
      }
      *(bf16x4*)&Pw[((t ^ kx) << 3) + 4 * h5]       = p0;
      *(bf16x4*)&Pw[(((t + 4) ^ kx) << 3) + 4 * h5] = p1;
    }
    // ---- PV: A = P[q][k] fragments, B = V[k][d] fragments; ones-MFMA row-sum
    bf16x8 pa[4];
#pragma unroll
    for (int s = 0; s < 4; ++s)
      pa[s] = *(const bf16x8*)&Pw[((2 * s + h5) ^ kx) << 3];
    __builtin_amdgcn_s_setprio(1);
#pragma unroll
    for (int s = 0; s < 4; ++s) ol = MFMA32(pa[s], ones, ol);
#pragma unroll
    for (int s = 0; s < 4; ++s) {
      const int eoff = ((2 * s + h5) ^ kx) << 3;
      bf16x8 vf0 = *(const bf16x8*)&kv[kB + 4096 + q_l * 64 + eoff];
      bf16x8 vf1 = *(const bf16x8*)&kv[kB + 4096 + (32 + q_l) * 64 + eoff];
      oa0 = MFMA32(pa[s], vf0, oa0);
      oa1 = MFMA32(pa[s], vf1, oa1);
    }
    __builtin_amdgcn_s_setprio(0);
  };

  // prologue: stage tile 0 into buf0
  STAGE(0, 0);
  asm volatile("s_waitcnt vmcnt(0)" ::: "memory");
  __syncthreads();

  for (int it = 0; it < 16; ++it) {
    const int t0 = it * 128;
    STAGE(8192, t0 + 64);                    // stage odd tile into buf1
    TILE(0);
    asm volatile("s_waitcnt vmcnt(0)" ::: "memory");
    __syncthreads();
    if (it < 15) STAGE(0, t0 + 128);         // stage even tile into buf0
    TILE(1);
    asm volatile("s_waitcnt vmcnt(0)" ::: "memory");
    __syncthreads();
  }

  // epilogue: oa and ol share the C/D row mapping -> shuffle-free normalize
#pragma unroll
  for (int r = 0; r < 16; ++r) {
    const int qr = (r & 3) + 8 * (r >> 2) + 4 * h5;
    const float inv = 1.0f / ol[r];
    const size_t rowb = (size_t)(b * Seq + q0w + qr) * 512 + h * 64;
    A2[rowb + q_l]      = (bf16)(oa0[r] * inv);
    A2[rowb + 32 + q_l] = (bf16)(oa1[r] * inv);
  }
}

extern "C" void kernel_launch(void* const* d_in, const int* in_sizes, int n_in,
                              void* d_out, int out_size, void* d_ws, size_t ws_size,
                              hipStream_t stream) {
  const float* x    = (const float*)d_in[0];
  const float* gam  = (const float*)d_in[1];
  const float* bet  = (const float*)d_in[2];
  const float* wqkv = (const float*)d_in[3];  // [512][1536]
  const float* wout = (const float*)d_in[4];  // [512][512]
  const float* bout = (const float*)d_in[5];  // [512]
  float* out = (float*)d_out;

  bf16* xn    = (bf16*)d_ws;                        // [8192][512]   8 MB
  bf16* wqkvT = xn    + (size_t)8192 * 512;         // [1536][512]   1.5 MB
  bf16* woutT = wqkvT + (size_t)1536 * 512;         // [512][512]    0.5 MB
  bf16* Qb    = woutT + (size_t)512 * 512;          // [4,8,2048,64] 8 MB
  bf16* Kb    = Qb    + (size_t)4 * 8 * 2048 * 64;
  bf16* VT    = Kb    + (size_t)4 * 8 * 2048 * 64;  // [4,8,64,2048] 8 MB
  bf16* A2    = xn;  // reuse: xn dead after QKV GEMM

  // 64^-0.5 * log2(e) folded into Q columns of w_qkv
  const float K1 = 0.18033688011112042f;

  ln_cast_kernel<<<2048, 256, 0, stream>>>(x, gam, bet, xn);
  tcast_kernel<<<dim3(48, 16), 256, 0, stream>>>(wqkv, wqkvT, 512, 1536, 512, K1);
  tcast_kernel<<<dim3(16, 16), 256, 0, stream>>>(wout, woutT, 512, 512, 0, 1.0f);
  gemm_qkv_kernel<<<dim3(64, 12), 256, 0, stream>>>(xn, wqkvT, Qb, Kb, VT);
  attn7_kernel<<<dim3(16, 32), 256, 0, stream>>>(Qb, Kb, VT, A2);
  gemm_out_kernel<<<dim3(64, 4), 256, 0, stream>>>(A2, woutT, bout, out);
}